// Round 12
// baseline (233.797 us; speedup 1.0000x reference)
//
#include <hip/hip_runtime.h>
#include <math.h>

// Problem constants (fixed by setup_inputs)
#define NB 32
#define NN 512
#define NL 2048
#define NSEG 15
#define NFREQ 129
#define KREF 16
#define EPS_S 2.25e-10f   // 1e-12 * NSEG^2 (coherence on raw sums; herm 2x-scale cancels per-bin)

// ws layout (in floats):
//   Xg : per (b,s) row, 64 float4 (lane-ordered bin pairs {X[2m],X[2m+1]}, m=br6(lane))
//        + X[128] (real) at float index 256; row stride 260 floats
//   scores: float[NB][NN] ; idx: int[NB][KREF]
#define XROW_F    260
#define XG_FLOATS (NB*NSEG*XROW_F)
#define SC_OFF    XG_FLOATS
#define IDX_OFF   (SC_OFF + NB*NN)

// ---- packed 2xf32 (targets v_pk_*_f32 on CDNA) ----
typedef float f2 __attribute__((ext_vector_type(2)));
typedef unsigned u32x2 __attribute__((ext_vector_type(2)));
__device__ __forceinline__ f2 mkf2(float a, float b){ f2 r; r.x=a; r.y=b; return r; }
__device__ __forceinline__ f2 swp(f2 v){ return __builtin_shufflevector(v, v, 1, 0); }
#if defined(__has_builtin)
#  if __has_builtin(__builtin_elementwise_fma)
#    define EF(a,b,c) __builtin_elementwise_fma((a),(b),(c))
#  endif
#endif
#ifndef EF
#  define EF(a,b,c) ((a)*(b)+(c))
#endif

// ---- cross-lane helpers on the VALU pipe (DPP / permlane), guarded ----
#if defined(__has_builtin)
#  if __has_builtin(__builtin_amdgcn_mov_dpp)
#    define HAVE_DPP 1
#  endif
#  if __has_builtin(__builtin_amdgcn_permlane32_swap)
#    define HAVE_PL32 1
#  endif
#  if __has_builtin(__builtin_amdgcn_permlane16_swap)
#    define HAVE_PL16 1
#  endif
#endif

__device__ __forceinline__ float xor1f(float x) {
#ifdef HAVE_DPP
    return __int_as_float(__builtin_amdgcn_mov_dpp(__float_as_int(x), 0xB1, 0xF, 0xF, true)); // quad_perm(1,0,3,2)
#else
    return __shfl_xor(x, 1, 64);
#endif
}
__device__ __forceinline__ float xor2f(float x) {
#ifdef HAVE_DPP
    return __int_as_float(__builtin_amdgcn_mov_dpp(__float_as_int(x), 0x4E, 0xF, 0xF, true)); // quad_perm(2,3,0,1)
#else
    return __shfl_xor(x, 2, 64);
#endif
}
__device__ __forceinline__ float xor8f(float x) {
#ifdef HAVE_DPP
    // row_ror:8 (0x128): within each 16-lane DPP row, lane i reads (i+8)%16 == i^8
    return __int_as_float(__builtin_amdgcn_mov_dpp(__float_as_int(x), 0x128, 0xF, 0xF, true));
#else
    return __shfl_xor(x, 8, 64);
#endif
}

// permlane self-swap: outputs (o0,o1) with per-lane SET {o0[i],o1[i]} = {x[i], x[i^32]}.
// Consumers use only the convention-independent sum o0+o1 = x + x[i^32].
__device__ __forceinline__ void plswap32(float x, float& o0, float& o1) {
#ifdef HAVE_PL32
    u32x2 r = __builtin_amdgcn_permlane32_swap(__float_as_uint(x), __float_as_uint(x), false, false);
    o0 = __uint_as_float(r.x); o1 = __uint_as_float(r.y);
#else
    o0 = x; o1 = __shfl_xor(x, 32, 64);
#endif
}
__device__ __forceinline__ void plswap16(float x, float& o0, float& o1) {
#ifdef HAVE_PL16
    u32x2 r = __builtin_amdgcn_permlane16_swap(__float_as_uint(x), __float_as_uint(x), false, false);
    o0 = __uint_as_float(r.x); o1 = __uint_as_float(r.y);
#else
    o0 = x; o1 = __shfl_xor(x, 16, 64);
#endif
}
// s[i] = v[i] + v[i^32] (per component), on the VALU pipe
__device__ __forceinline__ f2 xsum32(f2 v) {
    float a0,a1,b0,b1;
    plswap32(v.x, a0, a1); plswap32(v.y, b0, b1);
    return mkf2(a0,b0) + mkf2(a1,b1);
}
__device__ __forceinline__ f2 xsum16(f2 v) {
    float a0,a1,b0,b1;
    plswap16(v.x, a0, a1); plswap16(v.y, b0, b1);
    return mkf2(a0,b0) + mkf2(a1,b1);
}
__device__ __forceinline__ float xsum32s(float x){ float a,b; plswap32(x,a,b); return a+b; }
__device__ __forceinline__ float xsum16s(float x){ float a,b; plswap16(x,a,b); return a+b; }

__device__ __forceinline__ int br6(int x) { return (int)(__brev((unsigned)x) >> 26); }

// packed-pair cross-lane exchange (DS / DPP)
#define XPAIR_DS(v, h) mkf2(__shfl_xor((v).x, (h), 64), __shfl_xor((v).y, (h), 64))
#define XPAIR8(v)      mkf2(xor8f((v).x), xor8f((v).y))
#define XPAIR2(v)      mkf2(xor2f((v).x), xor2f((v).y))
#define XPAIR1(v)      mkf2(xor1f((v).x), xor1f((v).y))

struct WaveFFT {
    f2 w01, w23;             // hann window pairs {w[2t],w[2t+1]}, {w[2t+128],w[2t+129]}
    f2 T64A, T64B;           // stage64 twiddle: A={c,c}, B={-s,s}
    f2 twA[6], twB[6];       // per cross-lane stage (identity {1,1}/{0,0} for lower lanes)
    f2 sg2[6];               // {sg,sg} (used by stages 2..5)
    f2 cm32, cm16;           // {sg-1}: 0 lower / -2 upper, for sum-form butterflies
    f2 WkA0, WkB0, WkA1, WkB1; // herm W_256^{2m}, W_256^{2m+1}
    float cm0, cm1;          // detrend post-correction masks: -(t==0), +0.5*(t==0)
    int cs0;                 // conjugate-partner source lane for slot0 (slot1 = t^63)
};

__device__ __forceinline__ void wfft_init(WaveFFT& P, int t)
{
    const float PI = 3.14159265358979323846f;
    float s, c;
    P.w01 = mkf2(0.5f - 0.5f*cosf((float)(2*t    )*(PI/128.0f)),
                 0.5f - 0.5f*cosf((float)(2*t + 1)*(PI/128.0f)));
    P.w23 = mkf2(0.5f - 0.5f*cosf((float)(2*t+128)*(PI/128.0f)),
                 0.5f - 0.5f*cosf((float)(2*t+129)*(PI/128.0f)));
    sincosf(-PI*(float)t/64.0f, &s, &c);
    P.T64A = mkf2(c, c);  P.T64B = mkf2(-s, s);
#pragma unroll
    for (int st = 0; st < 6; ++st) {
        int h   = 32 >> st;
        int pos = t & (h-1);
        sincosf(-PI*(float)pos/(float)h, &s, &c);
        int up = (t & h);
        P.sg2[st] = up ? mkf2(-1.f,-1.f) : mkf2(1.f,1.f);
        P.twA[st] = up ? mkf2(c, c)      : mkf2(1.f,1.f);
        P.twB[st] = up ? mkf2(-s, s)     : mkf2(0.f,0.f);
    }
    P.cm32 = (t & 32) ? mkf2(-2.f,-2.f) : mkf2(0.f,0.f);
    P.cm16 = (t & 16) ? mkf2(-2.f,-2.f) : mkf2(0.f,0.f);
    const int m = br6(t);
    sincosf(-PI*(float)(2*m  )/128.0f, &s, &c); P.WkA0 = mkf2(c,c); P.WkB0 = mkf2(-s,s);
    sincosf(-PI*(float)(2*m+1)/128.0f, &s, &c); P.WkA1 = mkf2(c,c); P.WkB1 = mkf2(-s,s);
    P.cm0 = (t == 0) ? -1.0f : 0.0f;
    P.cm1 = (t == 0) ?  0.5f : 0.0f;
    P.cs0 = br6((64 - m) & 63);   // lane whose slot0 = Z[(128-2m)%128]
    // slot1 partner lane br6(63-m) == 63-t == t^63 (bit-reversal of complement)
}

// butterfly, partner form: z' = tw * (p + sg*z)
__device__ __forceinline__ void bfly2(f2& z0, f2& z1, f2 p0, f2 p1, f2 sg, f2 tA, f2 tB)
{
    f2 b0 = EF(sg, z0, p0), b1 = EF(sg, z1, p1);
    z0 = EF(b0, tA, swp(b0)*tB);
    z1 = EF(b1, tA, swp(b1)*tB);
}
// butterfly, sum form (permlane stages): s = z + partner; z' = tw * (s + (sg-1)*z)
__device__ __forceinline__ void bfly2s(f2& z0, f2& z1, f2 s0, f2 s1, f2 cm, f2 tA, f2 tB)
{
    f2 b0 = EF(cm, z0, s0), b1 = EF(cm, z1, s1);
    z0 = EF(b0, tA, swp(b0)*tB);
    z1 = EF(b1, tA, swp(b1)*tB);
}

// Hermitian unpack, 2x-scaled (0.5s dropped; coherence is per-bin scale-invariant)
__device__ __forceinline__ f2 herm2(f2 z, f2 Zc, f2 WkA, f2 WkB)
{
    const f2 pm = mkf2(1.f, -1.f);
    f2 E = EF(Zc, pm, z);
    f2 O = EF(swp(z), pm, swp(Zc));
    return EF(O, WkA, EF(swp(O), WkB, E));
}

// One Welch segment (packed core; permlane stages 32/16; post-FFT detrend).
// Lane t (m=br6(t)) outputs bins 2m (Y0), 2m+1 (Y1); Y128 valid on lane 0 only.
__device__ __forceinline__ void seg_spectrum(f2 a0, f2 a1, int t, const WaveFFT& P,
                                             f2& Y0, f2& Y1, float& Y128)
{
    f2 z0 = a0 * P.w01;          // windowed, not detrended
    f2 z1 = a1 * P.w23;

    // raw-sum reduce (independent chain; consumed only at the bin-0/1 correction)
    float sm = (a0.x + a0.y) + (a1.x + a1.y);
    sm = xsum32s(sm);
    sm = xsum16s(sm);
    sm += xor8f(sm);
    sm += __shfl_xor(sm,  4, 64);
    sm += xor2f(sm);
    sm += xor1f(sm);

    { f2 u = z0 + z1, d = z0 - z1;          // stage h=64 (in-lane)
      z0 = u;  z1 = EF(d, P.T64A, swp(d)*P.T64B); }

    { f2 s0 = xsum32(z0), s1 = xsum32(z1);  // h=32 via permlane (VALU)
      bfly2s(z0, z1, s0, s1, P.cm32, P.twA[0], P.twB[0]); }
    { f2 s0 = xsum16(z0), s1 = xsum16(z1);  // h=16 via permlane (VALU)
      bfly2s(z0, z1, s0, s1, P.cm16, P.twA[1], P.twB[1]); }
    bfly2(z0, z1, XPAIR8(z0),      XPAIR8(z1),      P.sg2[2], P.twA[2], P.twB[2]);
    bfly2(z0, z1, XPAIR_DS(z0, 4), XPAIR_DS(z1, 4), P.sg2[3], P.twA[3], P.twB[3]);
    bfly2(z0, z1, XPAIR2(z0),      XPAIR2(z1),      P.sg2[4], P.twA[4], P.twB[4]);
    bfly2(z0, z1, XPAIR1(z0),      XPAIR1(z1),      P.sg2[5], P.twA[5], P.twB[5]);

    f2 Zc0 = mkf2(__shfl(z0.x, P.cs0, 64), __shfl(z0.y, P.cs0, 64));
    f2 Zc1 = XPAIR_DS(z1, 63);              // slot1 partner lane = t^63

    Y0 = herm2(z0, Zc0, P.WkA0, P.WkB0);
    Y1 = herm2(z1, Zc1, P.WkA1, P.WkB1);
    Y0.x = fmaf(sm, P.cm0, Y0.x);   // bin 0:  2X[0] = 2*sum(wx) - sum
    Y1.x = fmaf(sm, P.cm1, Y1.x);   // bin 1:  2X[1] = 2*Xraw[1] + 0.5*sum
    Y128 = Zc0.x - Zc0.y;           // lane 0: X[128] (W[128]=0: no correction)
}

// Two overlapping segments as two independent interleaved chains (packed core).
__device__ __forceinline__ void seg_spectrum_dual(
    f2 hA, f2 hB, f2 hC, int t, const WaveFFT& P,
    f2& YA0, f2& YA1, float& YA128,
    f2& YB0, f2& YB1, float& YB128)
{
    f2 zA0 = hA * P.w01, zA1 = hB * P.w23;
    f2 zB0 = hB * P.w01, zB1 = hC * P.w23;

    // both chains' raw-sum reduces packed into one f2 {sumA, sumB}
    f2 r = mkf2((hA.x + hA.y) + (hB.x + hB.y), (hB.x + hB.y) + (hC.x + hC.y));
    r = xsum32(r);
    r = xsum16(r);
    r += XPAIR8(r);
    r += XPAIR_DS(r, 4);
    r += XPAIR2(r);
    r += XPAIR1(r);

    { f2 u = zA0 + zA1, d = zA0 - zA1;  zA0 = u;  zA1 = EF(d, P.T64A, swp(d)*P.T64B); }
    { f2 u = zB0 + zB1, d = zB0 - zB1;  zB0 = u;  zB1 = EF(d, P.T64A, swp(d)*P.T64B); }

    // h=32, h=16 via permlane (VALU pipe, convention-free sum form)
    {
        f2 sA0 = xsum32(zA0), sA1 = xsum32(zA1);
        f2 sB0 = xsum32(zB0), sB1 = xsum32(zB1);
        bfly2s(zA0, zA1, sA0, sA1, P.cm32, P.twA[0], P.twB[0]);
        bfly2s(zB0, zB1, sB0, sB1, P.cm32, P.twA[0], P.twB[0]);
    }
    {
        f2 sA0 = xsum16(zA0), sA1 = xsum16(zA1);
        f2 sB0 = xsum16(zB0), sB1 = xsum16(zB1);
        bfly2s(zA0, zA1, sA0, sA1, P.cm16, P.twA[1], P.twB[1]);
        bfly2s(zB0, zB1, sB0, sB1, P.cm16, P.twA[1], P.twB[1]);
    }
    // h=8 (DPP)
    bfly2(zA0, zA1, XPAIR8(zA0), XPAIR8(zA1), P.sg2[2], P.twA[2], P.twB[2]);
    bfly2(zB0, zB1, XPAIR8(zB0), XPAIR8(zB1), P.sg2[2], P.twA[2], P.twB[2]);
    // h=4 (ds)
    {
        f2 pA0 = XPAIR_DS(zA0,4), pA1 = XPAIR_DS(zA1,4);
        f2 pB0 = XPAIR_DS(zB0,4), pB1 = XPAIR_DS(zB1,4);
        bfly2(zA0, zA1, pA0, pA1, P.sg2[3], P.twA[3], P.twB[3]);
        bfly2(zB0, zB1, pB0, pB1, P.sg2[3], P.twA[3], P.twB[3]);
    }
    // h=2, h=1 (DPP)
    bfly2(zA0, zA1, XPAIR2(zA0), XPAIR2(zA1), P.sg2[4], P.twA[4], P.twB[4]);
    bfly2(zB0, zB1, XPAIR2(zB0), XPAIR2(zB1), P.sg2[4], P.twA[4], P.twB[4]);
    bfly2(zA0, zA1, XPAIR1(zA0), XPAIR1(zA1), P.sg2[5], P.twA[5], P.twB[5]);
    bfly2(zB0, zB1, XPAIR1(zB0), XPAIR1(zB1), P.sg2[5], P.twA[5], P.twB[5]);

    f2 cA0 = mkf2(__shfl(zA0.x, P.cs0, 64), __shfl(zA0.y, P.cs0, 64));
    f2 cB0 = mkf2(__shfl(zB0.x, P.cs0, 64), __shfl(zB0.y, P.cs0, 64));
    f2 cA1 = XPAIR_DS(zA1, 63);
    f2 cB1 = XPAIR_DS(zB1, 63);

    YA0 = herm2(zA0, cA0, P.WkA0, P.WkB0);  YA1 = herm2(zA1, cA1, P.WkA1, P.WkB1);
    YB0 = herm2(zB0, cB0, P.WkA0, P.WkB0);  YB1 = herm2(zB1, cB1, P.WkA1, P.WkB1);
    YA0.x = fmaf(r.x, P.cm0, YA0.x);  YA1.x = fmaf(r.x, P.cm1, YA1.x);
    YB0.x = fmaf(r.y, P.cm0, YB0.x);  YB1.x = fmaf(r.y, P.cm1, YB1.x);
    YA128 = cA0.x - cA0.y;
    YB128 = cB0.x - cB0.y;
}

// ---------------- kernel 1: target spectra, one wave per (b, s) ----------------
__global__ __launch_bounds__(256)
void spectra_target(const float* __restrict__ tgt, float* __restrict__ wsf)
{
    const int t   = threadIdx.x & 63;
    const int wid = threadIdx.x >> 6;
    const int w   = blockIdx.x*4 + wid;   // 0..479
    const int b   = w / NSEG, s = w - b*NSEG;

    WaveFFT P; wfft_init(P, t);
    const f2* row2 = (const f2*)(tgt) + (size_t)b*(NL/2);
    f2 a0 = row2[(s << 6) + t];
    f2 a1 = row2[((s + 1) << 6) + t];
    f2 Y0, Y1; float Y128;
    seg_spectrum(a0, a1, t, P, Y0, Y1, Y128);
    float* Xrow = wsf + ((size_t)b*NSEG + s)*XROW_F;
    ((float4*)Xrow)[t] = make_float4(Y0.x, Y0.y, Y1.x, Y1.y);
    if (t == 0) Xrow[256] = Y128;
}

// ---------------- kernel 2: coherence scores (dominant) ----------------
__global__ __launch_bounds__(256)
void coherence_scores(const float* __restrict__ db, const float* __restrict__ wsf,
                      float* __restrict__ scores)
{
    const int t    = threadIdx.x & 63;
    const int wid  = threadIdx.x >> 6;
    const int pair = blockIdx.x*4 + wid;    // b*512 + n
    const int b    = pair >> 9;

    WaveFFT P; wfft_init(P, t);
    const f2* row2 = (const f2*)(db) + (size_t)pair*(NL/2);
    const float* Xg = wsf;

    f2 sxxP0 = mkf2(0,0), sxxP1 = mkf2(0,0);   // componentwise |X|^2 (sum .x+.y at end)
    f2 syyP0 = mkf2(0,0), syyP1 = mkf2(0,0);
    f2 sxy0  = mkf2(0,0), sxy1  = mkf2(0,0);   // {re, im} of sum conj(X)*Y
    float sxx128 = 0.f, syy128 = 0.f, sxy128 = 0.f;

    f2 hA = row2[t];            // half s
    f2 hB = row2[64 + t];       // half s+1
    for (int s = 0; s < NSEG-1; s += 2) {
        f2 hC = row2[((s + 2) << 6) + t];
        f2 hD = row2[((s + 3) << 6) + t];
        const float* XrowA = Xg + ((size_t)b*NSEG + s)*XROW_F;
        const float* XrowB = XrowA + XROW_F;
        float4 XqA = ((const float4*)XrowA)[t];
        float4 XqB = ((const float4*)XrowB)[t];
        float  XA128 = XrowA[256];
        float  XB128 = XrowB[256];

        f2 YA0, YA1, YB0, YB1; float YA128, YB128;
        seg_spectrum_dual(hA, hB, hC, t, P, YA0, YA1, YA128, YB0, YB1, YB128);
        hA = hC; hB = hD;

        {
            f2 X0 = mkf2(XqA.x, XqA.y), X1 = mkf2(XqA.z, XqA.w);
            sxxP0 = EF(X0, X0, sxxP0);   sxxP1 = EF(X1, X1, sxxP1);
            syyP0 = EF(YA0, YA0, syyP0); syyP1 = EF(YA1, YA1, syyP1);
            sxy0 = EF(YA0, mkf2(X0.x, X0.x), EF(swp(YA0), mkf2(X0.y, -X0.y), sxy0));
            sxy1 = EF(YA1, mkf2(X1.x, X1.x), EF(swp(YA1), mkf2(X1.y, -X1.y), sxy1));
            sxx128 += XA128*XA128;  syy128 += YA128*YA128;  sxy128 += XA128*YA128;
        }
        {
            f2 X0 = mkf2(XqB.x, XqB.y), X1 = mkf2(XqB.z, XqB.w);
            sxxP0 = EF(X0, X0, sxxP0);   sxxP1 = EF(X1, X1, sxxP1);
            syyP0 = EF(YB0, YB0, syyP0); syyP1 = EF(YB1, YB1, syyP1);
            sxy0 = EF(YB0, mkf2(X0.x, X0.x), EF(swp(YB0), mkf2(X0.y, -X0.y), sxy0));
            sxy1 = EF(YB1, mkf2(X1.x, X1.x), EF(swp(YB1), mkf2(X1.y, -X1.y), sxy1));
            sxx128 += XB128*XB128;  syy128 += YB128*YB128;  sxy128 += XB128*YB128;
        }
    }
    {   // tail segment 14 (hA=h14, hB=h15)
        const float* Xrow = Xg + ((size_t)b*NSEG + (NSEG-1))*XROW_F;
        float4 Xq   = ((const float4*)Xrow)[t];
        float  X128 = Xrow[256];
        f2 Y0, Y1; float Y128;
        seg_spectrum(hA, hB, t, P, Y0, Y1, Y128);
        f2 X0 = mkf2(Xq.x, Xq.y), X1 = mkf2(Xq.z, Xq.w);
        sxxP0 = EF(X0, X0, sxxP0);  sxxP1 = EF(X1, X1, sxxP1);
        syyP0 = EF(Y0, Y0, syyP0);  syyP1 = EF(Y1, Y1, syyP1);
        sxy0 = EF(Y0, mkf2(X0.x, X0.x), EF(swp(Y0), mkf2(X0.y, -X0.y), sxy0));
        sxy1 = EF(Y1, mkf2(X1.x, X1.x), EF(swp(Y1), mkf2(X1.y, -X1.y), sxy1));
        sxx128 += X128*X128;  syy128 += Y128*Y128;  sxy128 += X128*Y128;
    }

    float sxx0 = sxxP0.x + sxxP0.y, sxx1 = sxxP1.x + sxxP1.y;
    float syy0 = syyP0.x + syyP0.y, syy1 = syyP1.x + syyP1.y;
    float c0 = (sxy0.x*sxy0.x + sxy0.y*sxy0.y) / (sxx0*syy0 + EPS_S);
    float c1 = (sxy1.x*sxy1.x + sxy1.y*sxy1.y) / (sxx1*syy1 + EPS_S);
    float c128 = (sxy128*sxy128) / (sxx128*syy128 + EPS_S);
    float csum = c0 + c1 + ((t == 0) ? c128 : 0.0f);
    csum = xsum32s(csum);
    csum = xsum16s(csum);
    csum += xor8f(csum);
    csum += __shfl_xor(csum,  4, 64);
    csum += xor2f(csum);
    csum += xor1f(csum);
    if (t == 0) scores[pair] = csum * (1.0f/(float)NFREQ);
}

// ---------------- kernel 3: top-16 per batch (ties -> lower index) ----------------
__global__ __launch_bounds__(256)
void topk_kernel(const float* __restrict__ scores, int* __restrict__ idx)
{
    __shared__ float sc[NN];
    __shared__ float bestv[4];
    __shared__ int   besti[4];
    const int b = blockIdx.x, tid = threadIdx.x;
    sc[tid]       = scores[b*NN + tid];
    sc[tid + 256] = scores[b*NN + tid + 256];
    __syncthreads();

    for (int j = 0; j < KREF; ++j) {
        float v0 = sc[tid], v1 = sc[tid + 256];
        float v; int i;
        if (v1 > v0) { v = v1; i = tid + 256; } else { v = v0; i = tid; }  // tie -> lower idx
#pragma unroll
        for (int m = 1; m < 64; m <<= 1) {
            float ov = __shfl_xor(v, m, 64);
            int   oi = __shfl_xor(i, m, 64);
            if (ov > v || (ov == v && oi < i)) { v = ov; i = oi; }
        }
        const int wid = tid >> 6;
        if ((tid & 63) == 0) { bestv[wid] = v; besti[wid] = i; }
        __syncthreads();
        if (tid == 0) {
            float bv = bestv[0]; int bi = besti[0];
#pragma unroll
            for (int w = 1; w < 4; ++w)
                if (bestv[w] > bv || (bestv[w] == bv && besti[w] < bi)) { bv = bestv[w]; bi = besti[w]; }
            idx[b*KREF + j] = bi;
            sc[bi] = -1e30f;
        }
        __syncthreads();
    }
}

// ---------------- kernel 4: gather top rows ----------------
__global__ __launch_bounds__(256)
void gather_kernel(const float* __restrict__ db, const int* __restrict__ idx,
                   float* __restrict__ out)
{
    const int blk = blockIdx.x;           // b*16 + j
    const int b = blk >> 4, j = blk & 15;
    const int row = idx[b*KREF + j];
    const float4* src = (const float4*)(db + ((size_t)b*NN + row)*NL);
    float4*       dst = (float4*)(out + ((size_t)b*KREF + j)*NL);
    dst[threadIdx.x]       = src[threadIdx.x];
    dst[threadIdx.x + 256] = src[threadIdx.x + 256];
}

extern "C" void kernel_launch(void* const* d_in, const int* in_sizes, int n_in,
                              void* d_out, int out_size, void* d_ws, size_t ws_size,
                              hipStream_t stream)
{
    const float* tgt = (const float*)d_in[0];   // [32,1,2048]
    const float* db  = (const float*)d_in[1];   // [32,512,2048]
    float* out = (float*)d_out;                 // [32,16,2048]
    float* wsf = (float*)d_ws;                  // ~566 KB of ws
    float* scores = wsf + SC_OFF;
    int*   idx    = (int*)(wsf + IDX_OFF);

    spectra_target  <<<(NB*NSEG)/4, 256, 0, stream>>>(tgt, wsf);
    coherence_scores<<<(NB*NN)/4,   256, 0, stream>>>(db, wsf, scores);
    topk_kernel     <<<NB,          256, 0, stream>>>(scores, idx);
    gather_kernel   <<<NB*KREF,     256, 0, stream>>>(db, idx, out);
}